// Round 5
// baseline (938.175 us; speedup 1.0000x reference)
//
#include <hip/hip_runtime.h>
#include <hip/hip_bf16.h>

#define HH 448
#define WW 512
#define CHW (HH*WW)          // channel stride in x_in = 229376
#define NPIX (HH*WW)         // 229376 pixels
#define WCH 64               // w-chunk per stage-1 block (halved: occupancy 2->4 blocks/CU)
#define LDW 72               // xs physical row stride (words), swizzled layout (64 cols + swz pad)

typedef unsigned short u16;
typedef __attribute__((ext_vector_type(8))) u16 ushort8v;

__device__ __forceinline__ float lrelu(float v) { return v >= 0.f ? v : 0.01f * v; }

__device__ __forceinline__ u16 f2bf(float v) {
    __hip_bfloat16 b = __float2bfloat16(v);
    union { __hip_bfloat16 h; u16 u; } cv; cv.h = b;
    return cv.u;
}

__device__ __forceinline__ float bf2f(u16 u) {
    union { unsigned int i; float f; } cv; cv.i = ((unsigned int)u) << 16;
    return cv.f;
}

// swizzled base word of 8-float group g (g = w>>3, g in 0..7): spreads groups over
// bank-quads -> 2-way aliasing (free, minimum for 64 lanes/32 banks). Max 67 -> LDW=72.
__device__ __forceinline__ int swz8(int g) { return g * 8 + ((g >> 2) << 2); }

// One GEMM phase: acc[o][w] += sum_k W[o][k] * xs[k][w], K=128, 64-col tile.
// 256 threads: og=tid>>4 (16 x 8 outputs), wg=tid&15 (16 x 4 cols).
// Weights read directly from global [o][k] row-major (the 16 wg-lanes of an og
// group broadcast the same address -> L1/L2-served). NO manual double-buffer
// (R3/R4 lesson: compiler scheduling wins; manual VGPR pipelining spills).
// No closing barrier — callers sync before reusing xs. Bias preloaded in biasv.
// Accumulation order over k strictly ascending -> bit-identical results.
// EXTRA: also accumulate row o=128 (O=129) into a128 on wave 0 (tid<64, col=tid).
template<bool EXTRA>
__device__ __forceinline__ void gemm_phase(
    const float* __restrict__ wsrc,
    const float* __restrict__ xs,
    float (&acc)[8][4], float& a128, int tid, int o0, int xoff, int swtid)
{
#pragma unroll
    for (int i = 0; i < 8; ++i)
#pragma unroll
        for (int j = 0; j < 4; ++j) acc[i][j] = 0.f;
    a128 = 0.f;

    __syncthreads();            // xs stable (prev epilogue done / x-load done)

    const float* wb   = wsrc + o0 * 128;    // this thread's 8 weight rows
    const float* w128 = wsrc + 128 * 128;   // row o=128 (EXTRA only)

#pragma unroll 2
    for (int k4 = 0; k4 < 32; ++k4) {
        // 8 row-major weight float4s: W[o0+i][4*k4 .. 4*k4+3] (broadcast loads)
        float4 wv[8];
#pragma unroll
        for (int i = 0; i < 8; ++i)
            wv[i] = *(const float4*)(wb + i * 128 + k4 * 4);
        // 4 xs rows x 4 cols
        float4 xv[4];
#pragma unroll
        for (int r = 0; r < 4; ++r)
            xv[r] = *(const float4*)(xs + (k4 * 4 + r) * LDW + xoff);
#pragma unroll
        for (int r = 0; r < 4; ++r) {
            const float xr4[4] = {xv[r].x, xv[r].y, xv[r].z, xv[r].w};
#pragma unroll
            for (int i = 0; i < 8; ++i) {
                const float ws4[4] = {wv[i].x, wv[i].y, wv[i].z, wv[i].w};
                const float wi = ws4[r];     // r compile-time after unroll
#pragma unroll
                for (int j = 0; j < 4; ++j)
                    acc[i][j] = fmaf(wi, xr4[j], acc[i][j]);
            }
        }
        if (EXTRA && tid < 64) {            // wave 0 only: uniform branch
            const float4 w4 = *(const float4*)(w128 + k4 * 4);   // wave-uniform
            const float w4a[4] = {w4.x, w4.y, w4.z, w4.w};
#pragma unroll
            for (int r = 0; r < 4; ++r)
                a128 = fmaf(w4a[r], xs[(k4 * 4 + r) * LDW + swtid], a128);
        }
    }
}

__global__ __launch_bounds__(256, 4) void stage1_kernel(
    const float* __restrict__ x_in,
    const float* __restrict__ w_cl1, const float* __restrict__ b_cl1,
    const float* __restrict__ w_cl2, const float* __restrict__ b_cl2,
    const float* __restrict__ w_cl3, const float* __restrict__ b_cl3,
    const float* __restrict__ w_reg1, const float* __restrict__ b_reg1,
    u16* __restrict__ xr_ws, int* __restrict__ inds_ws, float* __restrict__ out)
{
    __shared__ float xs[128 * LDW];     // 36,864 B : x -> t1 -> t2 (single live buffer)
    __shared__ float biasv[4][132];     //  2,112 B : all 4 bias vectors, loaded once
    // total ~39 KB -> 4 blocks/CU (16 waves/CU, 4 waves/SIMD)

    const int tid = threadIdx.x;
    const int b = blockIdx.x;
    // swizzle: 8 consecutive b -> 8 different h (one per XCD); the 8 chunks of an
    // h sit at b == +8 steps -> same XCD slot under round-robin -> L2 weight reuse
    const int h     = (b >> 6) * 8 + (b & 7);
    const int chunk = (b >> 3) & 7;
    const int wbase = chunk * WCH;

    const int og = tid >> 4, wg = tid & 15;
    const int o0 = og * 8,  w0 = wg * 4;
    const int xoff  = swz8(wg >> 1) + (wg & 1) * 4;               // compute-loop x offset
    const int swtid = swz8(tid >> 3) + (tid & 7);                 // swizzled col=tid (tid<64)

    // ---- preload all biases (race-free: consumed only after barriers) ----
    if (tid < 128) {
        biasv[0][tid] = b_reg1[(size_t)h * 128 + tid];
        biasv[1][tid] = b_cl1 [(size_t)h * 128 + tid];
        biasv[2][tid] = b_cl2 [(size_t)h * 128 + tid];
    }
    if (tid < 129) biasv[3][tid] = b_cl3[(size_t)h * 129 + tid];

    // ---- load x chunk: xs[c][w] = x_in[c][h][wbase+w] (swizzled store) ----
    {
        const float* xg = x_in + h * WW + wbase;
#pragma unroll
        for (int it = 0; it < 8; ++it) {
            int slot = it * 256 + tid;       // 2048 float4 slots (128 c x 16 f4)
            int c = slot >> 4, w4 = slot & 15;
            float4 v = *(const float4*)(xg + (size_t)c * CHW + w4 * 4);
            *(float4*)(xs + c * LDW + swz8(w4 >> 1) + (w4 & 1) * 4) = v;
        }
    }
    // (gemm_phase's opening __syncthreads covers the x load + bias preload)

    float acc[8][4]; float a128;

    // ---- phase A: x_r = lrelu(Wr @ x + br) -> bf16 workspace, n-ordered ----
    gemm_phase<false>(w_reg1 + (size_t)h * 16384, xs, acc, a128, tid, o0, xoff, swtid);
    {
#pragma unroll
        for (int j = 0; j < 4; ++j) {
            const int n = (wbase + w0 + j) * HH + h;   // n = w*448 + h
            ushort8v pk;
#pragma unroll
            for (int i = 0; i < 8; ++i)
                pk[i] = f2bf(lrelu(acc[i][j] + biasv[0][o0 + i]));
            *(ushort8v*)(xr_ws + (size_t)n * 128 + o0) = pk;
        }
    }
    // no barrier needed: epilogue A touches only global memory

    // ---- phase B: t1 = lrelu(W1 @ x + b1) -> overwrite xs (x dead after) ----
    gemm_phase<false>(w_cl1 + (size_t)h * 16384, xs, acc, a128, tid, o0, xoff, swtid);
    __syncthreads();   // all xs reads done -> safe to overwrite
#pragma unroll
    for (int i = 0; i < 8; ++i) {
        float bo = biasv[1][o0 + i];
        *(float4*)(xs + (o0 + i) * LDW + xoff) =
            make_float4(lrelu(acc[i][0] + bo), lrelu(acc[i][1] + bo), lrelu(acc[i][2] + bo), lrelu(acc[i][3] + bo));
    }
    // (phase C's opening barrier orders these writes before its reads)

    // ---- phase C: t2 = lrelu(W2 @ t1 + b2) -> overwrite xs ----
    gemm_phase<false>(w_cl2 + (size_t)h * 16384, xs, acc, a128, tid, o0, xoff, swtid);
    __syncthreads();
#pragma unroll
    for (int i = 0; i < 8; ++i) {
        float bo = biasv[2][o0 + i];
        *(float4*)(xs + (o0 + i) * LDW + xoff) =
            make_float4(lrelu(acc[i][0] + bo), lrelu(acc[i][1] + bo), lrelu(acc[i][2] + bo), lrelu(acc[i][3] + bo));
    }

    // ---- phase D: cl = W3 @ t2 + b3 (O=129), argmax + mask ----
    gemm_phase<true>(w_cl3 + (size_t)h * 16512, xs, acc, a128, tid, o0, xoff, swtid);

    __syncthreads();   // xs compute reads done -> reuse as argmax scratch
    float* sval = xs;                       // [16 og groups][64 cols]
    int*   sidx = (int*)(xs + 1024);
#pragma unroll
    for (int j = 0; j < 4; ++j) {
        float bv = -3.4e38f; int bi = 0;
#pragma unroll
        for (int i = 0; i < 8; ++i) {
            float v = acc[i][j] + biasv[3][o0 + i];
            if (v > bv) { bv = v; bi = o0 + i; }   // strict > => first-max (numpy rule)
        }
        sval[og * 64 + (w0 + j)] = bv;
        sidx[og * 64 + (w0 + j)] = bi;
    }
    __syncthreads();
    if (tid < 64) {
        const int w = tid;
        float bv = sval[w]; int bi = sidx[w];
#pragma unroll
        for (int g = 1; g < 16; ++g) {
            float v = sval[g * 64 + w];
            if (v > bv) { bv = v; bi = sidx[g * 64 + w]; }
        }
        inds_ws[h * WW + wbase + w] = bi;                       // p-ordered
        out[NPIX + h * WW + wbase + w] = lrelu(a128 + biasv[3][128]);  // mask (fp32)
    }
}

__global__ __launch_bounds__(256, 4) void stage2_kernel(
    const u16* __restrict__ xr_ws, const int* __restrict__ inds_ws,
    const float* __restrict__ w2g, const float* __restrict__ b2g,
    const float* __restrict__ w3g, const float* __restrict__ b3g,
    float* __restrict__ out)
{
    const int lane = threadIdx.x & 63;
    const int n = blockIdx.x * 4 + (threadIdx.x >> 6);   // n-ordered: sequential gathers
    const unsigned un = (unsigned)n;
    const int h = un % 448u, w = un / 448u;              // output pixel p = h*512 + w
    // weight index: inds_r[n] = inds_flat[n] + (n>>9)*128  (inds_flat is p-ordered)
    const int idx = inds_ws[n] + ((n >> 9) << 7);

    const int c0 = lane << 1;
    const u16* rp = xr_ws + (size_t)n * 128 + c0;        // xr stored n-ordered
    const float r0 = bf2f(rp[0]), r1 = bf2f(rp[1]);

    // w2[idx] is [c][o] fp32, o-stride 1, c-stride 4: rows c0, c0+1 -> two float4
    const float* wrow = w2g + (size_t)idx * 512;
    const float4 wa = *(const float4*)(wrow + (c0 << 2));
    const float4 wb = *(const float4*)(wrow + (c0 << 2) + 4);

    float s0 = r0 * wa.x + r1 * wb.x;
    float s1 = r0 * wa.y + r1 * wb.y;
    float s2 = r0 * wa.z + r1 * wb.z;
    float s3 = r0 * wa.w + r1 * wb.w;
#pragma unroll
    for (int m = 1; m < 64; m <<= 1) {
        s0 += __shfl_xor(s0, m, 64);
        s1 += __shfl_xor(s1, m, 64);
        s2 += __shfl_xor(s2, m, 64);
        s3 += __shfl_xor(s3, m, 64);
    }
    if (lane == 0) {
        const float4 b2v = *(const float4*)(b2g + (idx << 2));
        const float4 w3v = *(const float4*)(w3g + (idx << 2));
        float rr = b3g[idx];
        rr += lrelu(s0 + b2v.x) * w3v.x;
        rr += lrelu(s1 + b2v.y) * w3v.y;
        rr += lrelu(s2 + b2v.z) * w3v.z;
        rr += lrelu(s3 + b2v.w) * w3v.w;
        const int p = h * WW + w;
        const float ind_local = (float)inds_ws[p];
        out[p] = (ind_local + rr) * 0.0078125f;
    }
}

extern "C" void kernel_launch(void* const* d_in, const int* in_sizes, int n_in,
                              void* d_out, int out_size, void* d_ws, size_t ws_size,
                              hipStream_t stream)
{
    const float* x_in   = (const float*)d_in[0];
    const float* w_cl1  = (const float*)d_in[1];
    const float* b_cl1  = (const float*)d_in[2];
    const float* w_cl2  = (const float*)d_in[3];
    const float* b_cl2  = (const float*)d_in[4];
    const float* w_cl3  = (const float*)d_in[5];
    const float* b_cl3  = (const float*)d_in[6];
    const float* w_reg1 = (const float*)d_in[7];
    const float* b_reg1 = (const float*)d_in[8];
    const float* w2     = (const float*)d_in[9];
    const float* b2     = (const float*)d_in[10];
    const float* w3     = (const float*)d_in[11];
    const float* b3     = (const float*)d_in[12];

    float* out = (float*)d_out;
    u16* xr_ws = (u16*)d_ws;                                        // 229376*128 bf16 = 58,720,256 B
    int* inds  = (int*)((char*)d_ws + (size_t)NPIX * 128 * 2);      // + 917,504 B

    stage1_kernel<<<dim3(448 * 8), dim3(256), 0, stream>>>(
        x_in, w_cl1, b_cl1, w_cl2, b_cl2, w_cl3, b_cl3, w_reg1, b_reg1,
        xr_ws, inds, out);

    stage2_kernel<<<dim3(NPIX / 4), dim3(256), 0, stream>>>(
        xr_ws, inds, w2, b2, w3, b3, out);
}

// Round 6
// 688.956 us; speedup vs baseline: 1.3617x; 1.3617x over previous
//
#include <hip/hip_runtime.h>
#include <hip/hip_bf16.h>

#define HH 448
#define WW 512
#define CHW (HH*WW)          // channel stride in x_in = 229376
#define NPIX (HH*WW)         // 229376 pixels
#define WCH 128              // w-chunk per stage-1 block
#define LDW 140              // xs physical row stride (words), swizzled layout

typedef unsigned short u16;
typedef __attribute__((ext_vector_type(8))) u16 ushort8v;

__device__ __forceinline__ float lrelu(float v) { return v >= 0.f ? v : 0.01f * v; }

__device__ __forceinline__ u16 f2bf(float v) {
    __hip_bfloat16 b = __float2bfloat16(v);
    union { __hip_bfloat16 h; u16 u; } cv; cv.h = b;
    return cv.u;
}

__device__ __forceinline__ float bf2f(u16 u) {
    union { unsigned int i; float f; } cv; cv.i = ((unsigned int)u) << 16;
    return cv.f;
}

// swizzled base word of 8-float group g (g = w>>3): spreads the 16 groups over
// 8 bank-quads -> 2-way aliasing (free) instead of 4-way. Max offset 132+7 -> LDW=140.
__device__ __forceinline__ int swz8(int g) { return g * 8 + ((g >> 2) << 2); }

// ===== stage 1: verbatim the measured-412us R2 configuration =====
// (R3/R4/R5 lessons: acc[8][8] is the only shape with sane codegen; manual
// VGPR double-buffering spills; occupancy is LDS-pinned at ~8 waves/CU in this
// structure regardless of WCH. Don't touch.)
template<bool EXTRA>
__device__ __forceinline__ void gemm_phase(
    const float* __restrict__ wsrc, const float* __restrict__ bsrc, int O,
    const float* __restrict__ xs, float* __restrict__ biasb,
    float (&acc)[8][8], float& a128, int tid, int o0, int xoff, int swtid)
{
#pragma unroll
    for (int i = 0; i < 8; ++i)
#pragma unroll
        for (int j = 0; j < 8; ++j) acc[i][j] = 0.f;
    a128 = 0.f;

    __syncthreads();            // xs stable (prev epilogue done), biasb free
    if (tid < O) biasb[tid] = bsrc[tid];

    const float* wb   = wsrc + o0 * 128;    // this thread's 8 weight rows
    const float* w128 = wsrc + 128 * 128;   // row o=128 (EXTRA only)

#pragma unroll 2
    for (int k4 = 0; k4 < 32; ++k4) {
        // 8 row-major weight float4s: W[o0+i][4*k4 .. 4*k4+3] (broadcast loads)
        float4 wv[8];
#pragma unroll
        for (int i = 0; i < 8; ++i)
            wv[i] = *(const float4*)(wb + i * 128 + k4 * 4);
        // 4 xs rows x 8 cols
        float4 xva[4], xvb[4];
#pragma unroll
        for (int r = 0; r < 4; ++r) {
            xva[r] = *(const float4*)(xs + (k4 * 4 + r) * LDW + xoff);
            xvb[r] = *(const float4*)(xs + (k4 * 4 + r) * LDW + xoff + 4);
        }
#pragma unroll
        for (int r = 0; r < 4; ++r) {
            const float xr8[8] = {xva[r].x, xva[r].y, xva[r].z, xva[r].w,
                                  xvb[r].x, xvb[r].y, xvb[r].z, xvb[r].w};
#pragma unroll
            for (int i = 0; i < 8; ++i) {
                const float ws4[4] = {wv[i].x, wv[i].y, wv[i].z, wv[i].w};
                const float wi = ws4[r];     // r compile-time after unroll
#pragma unroll
                for (int j = 0; j < 8; ++j)
                    acc[i][j] = fmaf(wi, xr8[j], acc[i][j]);
            }
        }
        if (EXTRA && tid < 128) {
            const float4 w4 = *(const float4*)(w128 + k4 * 4);   // wave-uniform
            a128 = fmaf(w4.x, xs[(k4 * 4 + 0) * LDW + swtid], a128);
            a128 = fmaf(w4.y, xs[(k4 * 4 + 1) * LDW + swtid], a128);
            a128 = fmaf(w4.z, xs[(k4 * 4 + 2) * LDW + swtid], a128);
            a128 = fmaf(w4.w, xs[(k4 * 4 + 3) * LDW + swtid], a128);
        }
    }

    __syncthreads();            // all xs reads done; biasb visible to epilogue
}

__global__ __launch_bounds__(256, 2) void stage1_kernel(
    const float* __restrict__ x_in,
    const float* __restrict__ w_cl1, const float* __restrict__ b_cl1,
    const float* __restrict__ w_cl2, const float* __restrict__ b_cl2,
    const float* __restrict__ w_cl3, const float* __restrict__ b_cl3,
    const float* __restrict__ w_reg1, const float* __restrict__ b_reg1,
    u16* __restrict__ xr_ws, int* __restrict__ inds_ws, float* __restrict__ out)
{
    __shared__ float xs[128 * LDW];     // 71,680 B : x -> t1 -> t2 (single live buffer)
    __shared__ float biasb[132];        //    528 B
    // total ~72.2 KB -> 2 blocks/CU (8 waves/CU)

    const int tid = threadIdx.x;
    const int b = blockIdx.x;
    // swizzle: all 4 chunks of an h temporally adjacent (L2 weight reuse)
    const int h     = (b >> 5) * 8 + (b & 7);
    const int chunk = (b >> 3) & 3;
    const int wbase = chunk * WCH;

    const int og = tid >> 4, wg = tid & 15;
    const int o0 = og * 8,  w0 = wg * 8;
    const int xoff  = swz8(wg);                                   // compute-loop x offset
    const int swtid = swz8(tid >> 3) + (tid & 7);                 // scalar swizzled col=tid

    // ---- load x chunk: xs[c][w] = x_in[c][h][wbase+w] (swizzled store) ----
    {
        const float* xg = x_in + h * WW + wbase;
#pragma unroll
        for (int it = 0; it < 16; ++it) {
            int slot = it * 256 + tid;       // 4096 float4 slots
            int c = slot >> 5, w4 = slot & 31;
            float4 v = *(const float4*)(xg + (size_t)c * CHW + w4 * 4);
            *(float4*)(xs + c * LDW + swz8(w4 >> 1) + (w4 & 1) * 4) = v;
        }
    }
    // (gemm_phase's opening __syncthreads covers the x load)

    float acc[8][8]; float a128;

    // ---- phase A: x_r = lrelu(Wr @ x + br) -> bf16 workspace, n-ordered ----
    gemm_phase<false>(w_reg1 + (size_t)h * 16384, b_reg1 + h * 128, 128, xs, biasb, acc, a128, tid, o0, xoff, swtid);
    {
#pragma unroll
        for (int j = 0; j < 8; ++j) {
            const int n = (wbase + w0 + j) * HH + h;   // n = w*448 + h
            ushort8v pk;
#pragma unroll
            for (int i = 0; i < 8; ++i)
                pk[i] = f2bf(lrelu(acc[i][j] + biasb[o0 + i]));
            *(ushort8v*)(xr_ws + (size_t)n * 128 + o0) = pk;
        }
    }

    // ---- phase B: t1 = lrelu(W1 @ x + b1) -> overwrite xs (x dead after) ----
    gemm_phase<false>(w_cl1 + (size_t)h * 16384, b_cl1 + h * 128, 128, xs, biasb, acc, a128, tid, o0, xoff, swtid);
    __syncthreads();   // all xs reads done -> safe to overwrite
#pragma unroll
    for (int i = 0; i < 8; ++i) {
        float bo = biasb[o0 + i];
        *(float4*)(xs + (o0 + i) * LDW + xoff) =
            make_float4(lrelu(acc[i][0] + bo), lrelu(acc[i][1] + bo), lrelu(acc[i][2] + bo), lrelu(acc[i][3] + bo));
        *(float4*)(xs + (o0 + i) * LDW + xoff + 4) =
            make_float4(lrelu(acc[i][4] + bo), lrelu(acc[i][5] + bo), lrelu(acc[i][6] + bo), lrelu(acc[i][7] + bo));
    }
    // (phase C's opening barrier orders these writes before its reads)

    // ---- phase C: t2 = lrelu(W2 @ t1 + b2) -> overwrite xs ----
    gemm_phase<false>(w_cl2 + (size_t)h * 16384, b_cl2 + h * 128, 128, xs, biasb, acc, a128, tid, o0, xoff, swtid);
    __syncthreads();
#pragma unroll
    for (int i = 0; i < 8; ++i) {
        float bo = biasb[o0 + i];
        *(float4*)(xs + (o0 + i) * LDW + xoff) =
            make_float4(lrelu(acc[i][0] + bo), lrelu(acc[i][1] + bo), lrelu(acc[i][2] + bo), lrelu(acc[i][3] + bo));
        *(float4*)(xs + (o0 + i) * LDW + xoff + 4) =
            make_float4(lrelu(acc[i][4] + bo), lrelu(acc[i][5] + bo), lrelu(acc[i][6] + bo), lrelu(acc[i][7] + bo));
    }

    // ---- phase D: cl = W3 @ t2 + b3 (O=129), argmax + mask ----
    gemm_phase<true>(w_cl3 + (size_t)h * 16512, b_cl3 + h * 129, 129, xs, biasb, acc, a128, tid, o0, xoff, swtid);

    __syncthreads();   // xs compute reads done -> reuse as argmax scratch
    float* sval = xs;
    int*   sidx = (int*)(xs + 2048);
#pragma unroll
    for (int j = 0; j < 8; ++j) {
        float bv = -3.4e38f; int bi = 0;
#pragma unroll
        for (int i = 0; i < 8; ++i) {
            float v = acc[i][j] + biasb[o0 + i];
            if (v > bv) { bv = v; bi = o0 + i; }   // strict > => first-max (numpy rule)
        }
        sval[og * 128 + (w0 + j)] = bv;
        sidx[og * 128 + (w0 + j)] = bi;
    }
    __syncthreads();
    if (tid < 128) {
        const int w = tid;
        float bv = sval[w]; int bi = sidx[w];
#pragma unroll
        for (int g = 1; g < 16; ++g) {
            float v = sval[g * 128 + w];
            if (v > bv) { bv = v; bi = sidx[g * 128 + w]; }
        }
        inds_ws[h * WW + wbase + w] = bi;                       // p-ordered
        out[NPIX + h * WW + wbase + w] = lrelu(a128 + biasb[128]);  // mask (fp32)
    }
}

// ===== stage 2: rewritten — 8 lanes per n, 32 n per block =====
// Old: 1 n per wave (8 FMA/lane vs 48 shuffle-reduce ops, 6-deep ds_bpermute
// chain, dependent tail gathers, 4 n/block). New: lane cg in [0,8) owns 16
// contiguous channels of n; wave reads xr 2KB fully contiguous; w2 row (2KB)
// streamed as 16 float4/lane; reduce is 3 shfl steps; b2/w3/b3 gathers issued
// BEFORE the dot so their latency overlaps it. fp32 sum order changes
// (sequential-per-lane + 3-level tree) — ~1e-7 relative perturbation, far
// under threshold; argmax path (stage1) untouched.
__global__ __launch_bounds__(256, 4) void stage2_kernel(
    const u16* __restrict__ xr_ws, const int* __restrict__ inds_ws,
    const float* __restrict__ w2g, const float* __restrict__ b2g,
    const float* __restrict__ w3g, const float* __restrict__ b3g,
    float* __restrict__ out)
{
    const int l  = threadIdx.x & 63;
    const int wv = threadIdx.x >> 6;                  // wave 0..3
    const int nl = l >> 3, cg = l & 7;
    const int n  = blockIdx.x * 32 + wv * 8 + nl;     // n-ordered: sequential gathers
    const unsigned un = (unsigned)n;
    const int h = un % 448u, w = un / 448u;           // output pixel p = h*512 + w
    // weight index: inds_r[n] = inds_flat[n] + (n>>9)*128  (inds_flat is p-ordered)
    const int idx = inds_ws[n] + ((n >> 9) << 7);

    // early tail-gathers (cg==0 lanes; latency overlaps the dot below)
    float4 b2v = make_float4(0.f, 0.f, 0.f, 0.f);
    float4 w3v = make_float4(0.f, 0.f, 0.f, 0.f);
    float  b3s = 0.f;
    int    indp = 0;
    const int p = h * WW + w;
    if (cg == 0) {
        b2v  = *(const float4*)(b2g + (idx << 2));
        w3v  = *(const float4*)(w3g + (idx << 2));
        b3s  = b3g[idx];
        indp = inds_ws[p];
    }

    // xr: 16 channels, contiguous 32 B/lane (wave covers 2 KB contiguous)
    const int c0 = cg << 4;
    const u16* rp = xr_ws + (size_t)n * 128 + c0;
    const ushort8v x0 = *(const ushort8v*)(rp);
    const ushort8v x1 = *(const ushort8v*)(rp + 8);

    // w2[idx] is [c][o] fp32, o-stride 1, c-stride 4: this lane streams 64
    // floats (16 float4) of its 16-channel slice
    const float* wrow = w2g + (size_t)idx * 512 + (c0 << 2);
    float s0 = 0.f, s1 = 0.f, s2 = 0.f, s3 = 0.f;
#pragma unroll
    for (int t = 0; t < 16; ++t) {
        const float4 w4 = *(const float4*)(wrow + t * 4);
        const float xc = bf2f(t < 8 ? x0[t] : x1[t - 8]);   // t compile-time
        s0 = fmaf(xc, w4.x, s0);
        s1 = fmaf(xc, w4.y, s1);
        s2 = fmaf(xc, w4.z, s2);
        s3 = fmaf(xc, w4.w, s3);
    }
#pragma unroll
    for (int m = 1; m < 8; m <<= 1) {
        s0 += __shfl_xor(s0, m, 64);
        s1 += __shfl_xor(s1, m, 64);
        s2 += __shfl_xor(s2, m, 64);
        s3 += __shfl_xor(s3, m, 64);
    }
    if (cg == 0) {
        float rr = b3s;
        rr += lrelu(s0 + b2v.x) * w3v.x;
        rr += lrelu(s1 + b2v.y) * w3v.y;
        rr += lrelu(s2 + b2v.z) * w3v.z;
        rr += lrelu(s3 + b2v.w) * w3v.w;
        out[p] = ((float)indp + rr) * 0.0078125f;
    }
}

extern "C" void kernel_launch(void* const* d_in, const int* in_sizes, int n_in,
                              void* d_out, int out_size, void* d_ws, size_t ws_size,
                              hipStream_t stream)
{
    const float* x_in   = (const float*)d_in[0];
    const float* w_cl1  = (const float*)d_in[1];
    const float* b_cl1  = (const float*)d_in[2];
    const float* w_cl2  = (const float*)d_in[3];
    const float* b_cl2  = (const float*)d_in[4];
    const float* w_cl3  = (const float*)d_in[5];
    const float* b_cl3  = (const float*)d_in[6];
    const float* w_reg1 = (const float*)d_in[7];
    const float* b_reg1 = (const float*)d_in[8];
    const float* w2     = (const float*)d_in[9];
    const float* b2     = (const float*)d_in[10];
    const float* w3     = (const float*)d_in[11];
    const float* b3     = (const float*)d_in[12];

    float* out = (float*)d_out;
    u16* xr_ws = (u16*)d_ws;                                        // 229376*128 bf16 = 58,720,256 B
    int* inds  = (int*)((char*)d_ws + (size_t)NPIX * 128 * 2);      // + 917,504 B

    stage1_kernel<<<dim3(448 * 4), dim3(256), 0, stream>>>(
        x_in, w_cl1, b_cl1, w_cl2, b_cl2, w_cl3, b_cl3, w_reg1, b_reg1,
        xr_ws, inds, out);

    stage2_kernel<<<dim3(NPIX / 32), dim3(256), 0, stream>>>(
        xr_ws, inds, w2, b2, w3, b3, out);
}